// Round 6
// baseline (135.309 us; speedup 1.0000x reference)
//
#include <hip/hip_runtime.h>

typedef __attribute__((ext_vector_type(8))) short short8;
typedef __attribute__((ext_vector_type(4))) float f32x4;

namespace {
constexpr long long OFF_CODES = 4194304;        // 8*128*4096
constexpr long long OFF_LOSS  = 4227072;        // + 8*4096
constexpr long long OFF_DIST  = 4227073;
constexpr float EPS = 5e-4f;                    // > 2*max dist err of bf16 product
// ws byte offsets
constexpr size_t WS_LACC = 0;
constexpr size_t WS_SCF  = 1024;                // 1024 f32
constexpr size_t WS_SZF  = 8192;                // 32768 f32 (ends 139264)
constexpr size_t WS_CBH  = 139264;              // 1024*128 u16 (ends 401408)
constexpr size_t WS_PM1  = 401408;              // [4][32768] f32 (ends 925696)
constexpr size_t WS_PM2  = 925696;              // [4][32768] f32 (ends 1449984)
constexpr size_t WS_PI1  = 1449984;             // [4][32768] i32 (ends 1974272)
}

__device__ __forceinline__ unsigned short bf_rne(float v) {
  unsigned int u = __float_as_uint(v);
  unsigned int r = u + 0x7FFFu + ((u >> 16) & 1u);
  return (unsigned short)(r >> 16);
}

// ---- prep: codebook -> bf16 + f32 norms (f64-accumulated); zero lacc ----
__global__ __launch_bounds__(256) void vq_prep(
    const float* __restrict__ cb, unsigned short* __restrict__ cbh,
    float* __restrict__ scf, double* lacc)
{
  const int tid = threadIdx.x;
  const int row = blockIdx.x * 4 + (tid >> 6);
  const int d = tid & 63;
  float v0 = cb[row * 128 + d];
  float v1 = cb[row * 128 + 64 + d];
  cbh[row * 128 + d]      = bf_rne(v0);
  cbh[row * 128 + 64 + d] = bf_rne(v1);
  float q0 = v0 * v0, q1 = v1 * v1;              // f32 squares (numpy chain)
  double s = (double)q0 + (double)q1;
#pragma unroll
  for (int msk = 1; msk <= 32; msk <<= 1) s += __shfl_xor(s, msk);
  if (d == 0) scf[row] = (float)s;
  if (blockIdx.x == 0 && tid == 0) *lacc = 0.0;
}

// ---- main: block = 32 rows x 256 codes; wave = 64 codes (4 windows of 16).
// Writes dist (nontemporal) + per-block argmin partials (m1,m2,i1) to ws.
__global__ __launch_bounds__(256, 3) void vq_main(
    const float* __restrict__ z, const unsigned short* __restrict__ cbh,
    const float* __restrict__ scf, float* __restrict__ szf,
    float* __restrict__ pm1, float* __restrict__ pm2, int* __restrict__ pi1,
    float* __restrict__ out)
{
  __shared__ __align__(16) unsigned short zh[32 * 136];
  __shared__ double part[32][8];
  __shared__ float szl[32];
  __shared__ float scfl[256];
  __shared__ float rm1[4][32], rm2[4][32];
  __shared__ int   ri1[4][32];

  const int tid = threadIdx.x;
  const int jtile = blockIdx.x & 3;
  const int rtile = blockIdx.x >> 2;
  const int jb = jtile * 256;
  const int R0 = rtile * 32;
  const int b  = R0 >> 12;
  const int t0 = R0 & 4095;
  const float* zb = z + (size_t)b * 524288;

  scfl[tid] = scf[jb + tid];

  {                                              // z -> bf16 LDS + ||z||^2 partials
    double ps = 0.0;
    int t = tid & 31;
#pragma unroll
    for (int k = 0; k < 16; ++k) {
      int d = k * 8 + (tid >> 5);
      float v = zb[(size_t)d * 4096 + t0 + t];
      float q = v * v; ps += (double)q;
      zh[t * 136 + d] = bf_rne(v);
    }
    part[t][tid >> 5] = ps;
  }
  __syncthreads();
  if (tid < 32) {
    double s = 0.0;
#pragma unroll
    for (int g = 0; g < 8; ++g) s += part[tid][g];
    float sz = (float)s;
    szl[tid] = sz;
    if (jtile == 0) szf[R0 + tid] = sz;          // one writer per row
  }
  __syncthreads();

  const int w = tid >> 6, l = tid & 63, lj = l & 15, lg = l >> 4;
  const int jw = jb + w * 64;                    // wave's j base

  short8 Ah[2][4];
#pragma unroll
  for (int tt = 0; tt < 2; ++tt)
#pragma unroll
    for (int ks = 0; ks < 4; ++ks)
      Ah[tt][ks] = *reinterpret_cast<const short8*>(
          &zh[(tt * 16 + lj) * 136 + ks * 32 + lg * 8]);
  float szr[2][4];
#pragma unroll
  for (int tt = 0; tt < 2; ++tt)
#pragma unroll
    for (int r = 0; r < 4; ++r) szr[tt][r] = szl[tt * 16 + lg * 4 + r];

  const unsigned short* pb = cbh + (size_t)(jw + lj) * 128 + lg * 8;

  f32x4 acc[2][4];
#pragma unroll
  for (int u = 0; u < 4; ++u) {
    acc[0][u] = (f32x4){0.f, 0.f, 0.f, 0.f};
    acc[1][u] = (f32x4){0.f, 0.f, 0.f, 0.f};
    short8 bh0 = *reinterpret_cast<const short8*>(pb + (size_t)u * 2048);
    short8 bh1 = *reinterpret_cast<const short8*>(pb + (size_t)u * 2048 + 32);
    short8 bh2 = *reinterpret_cast<const short8*>(pb + (size_t)u * 2048 + 64);
    short8 bh3 = *reinterpret_cast<const short8*>(pb + (size_t)u * 2048 + 96);
    acc[0][u] = __builtin_amdgcn_mfma_f32_16x16x32_bf16(Ah[0][0], bh0, acc[0][u], 0, 0, 0);
    acc[1][u] = __builtin_amdgcn_mfma_f32_16x16x32_bf16(Ah[1][0], bh0, acc[1][u], 0, 0, 0);
    acc[0][u] = __builtin_amdgcn_mfma_f32_16x16x32_bf16(Ah[0][1], bh1, acc[0][u], 0, 0, 0);
    acc[1][u] = __builtin_amdgcn_mfma_f32_16x16x32_bf16(Ah[1][1], bh1, acc[1][u], 0, 0, 0);
    acc[0][u] = __builtin_amdgcn_mfma_f32_16x16x32_bf16(Ah[0][2], bh2, acc[0][u], 0, 0, 0);
    acc[1][u] = __builtin_amdgcn_mfma_f32_16x16x32_bf16(Ah[1][2], bh2, acc[1][u], 0, 0, 0);
    acc[0][u] = __builtin_amdgcn_mfma_f32_16x16x32_bf16(Ah[0][3], bh3, acc[0][u], 0, 0, 0);
    acc[1][u] = __builtin_amdgcn_mfma_f32_16x16x32_bf16(Ah[1][3], bh3, acc[1][u], 0, 0, 0);
  }

  float m1[8], m2[8]; int i1[8];
#pragma unroll
  for (int s = 0; s < 8; ++s) { m1[s] = 3.4e38f; m2[s] = 3.4e38f; i1[s] = 0; }

  // epilogue: numpy chain fl(fl(sz - 2m) + sc), min1/min2, nontemporal store
#pragma unroll
  for (int tt = 0; tt < 2; ++tt)
#pragma unroll
    for (int r = 0; r < 4; ++r) {
      const int s = tt * 4 + r;
      const float sz = szr[tt][r];
      float* orow = out + OFF_DIST
                  + (size_t)(R0 + tt * 16 + lg * 4 + r) * 1024 + jw + lj;
#pragma unroll
      for (int u = 0; u < 4; ++u) {              // j ascending within lane
        float dv = (sz - 2.0f * acc[tt][u][r]) + scfl[w * 64 + u * 16 + lj];
        bool lt1 = dv < m1[s];
        float o1 = m1[s];
        m2[s] = lt1 ? o1 : fminf(m2[s], dv);
        m1[s] = lt1 ? dv : o1;
        i1[s] = lt1 ? (jw + u * 16 + lj) : i1[s];
        __builtin_nontemporal_store(dv, orow + u * 16);
      }
    }

  // in-wave 16-lane lexicographic (val,idx) reduce, tracking min2
#pragma unroll
  for (int s = 0; s < 8; ++s) {
    float a1 = m1[s]; int ai = i1[s]; float a2 = m2[s];
#pragma unroll
    for (int msk = 1; msk <= 8; msk <<= 1) {
      float b1 = __shfl_xor(a1, msk);
      int   bi = __shfl_xor(ai, msk);
      float b2 = __shfl_xor(a2, msk);
      bool keep = (a1 < b1) || (a1 == b1 && ai < bi);
      float lose = keep ? b1 : a1;
      a2 = fminf(fminf(a2, b2), lose);
      ai = keep ? ai : bi;
      a1 = keep ? a1 : b1;
    }
    if (lj == 0) {
      int t = (s >> 2) * 16 + lg * 4 + (s & 3);
      rm1[w][t] = a1; ri1[w][t] = ai; rm2[w][t] = a2;
    }
  }
  __syncthreads();
  if (tid < 32) {                                // merge 4 waves (j ascending)
    float f1 = rm1[0][tid]; int fi = ri1[0][tid]; float f2 = rm2[0][tid];
#pragma unroll
    for (int ww = 1; ww < 4; ++ww) {
      float b1 = rm1[ww][tid]; int bi = ri1[ww][tid]; float b2 = rm2[ww][tid];
      bool keep = (f1 < b1) || (f1 == b1 && fi < bi);
      float lose = keep ? b1 : f1;
      f2 = fminf(fminf(f2, b2), lose);
      fi = keep ? fi : bi;
      f1 = keep ? f1 : b1;
    }
    int R = R0 + tid;
    pm1[jtile * 32768 + R] = f1;
    pm2[jtile * 32768 + R] = f2;
    pi1[jtile * 32768 + R] = fi;
  }
}

// ---- refine: merge 4 j-tile partials -> codes; exact recompute if ambiguous ----
__global__ __launch_bounds__(256) void vq_refine(
    const float* __restrict__ z, const float* __restrict__ cb,
    const float* __restrict__ scf, const float* __restrict__ szf,
    const float* __restrict__ pm1, const float* __restrict__ pm2,
    const int* __restrict__ pi1, float* __restrict__ out)
{
  const int w = threadIdx.x >> 6, l = threadIdx.x & 63;
  const int R = blockIdx.x * 4 + w;

  float f1 = pm1[R]; int fi = pi1[R]; float f2 = pm2[R];
#pragma unroll
  for (int jt = 1; jt < 4; ++jt) {
    float b1 = pm1[jt * 32768 + R];
    int   bi = pi1[jt * 32768 + R];
    float b2 = pm2[jt * 32768 + R];
    bool keep = (f1 < b1) || (f1 == b1 && fi < bi);
    float lose = keep ? b1 : f1;
    f2 = fminf(fminf(f2, b2), lose);
    fi = keep ? fi : bi;
    f1 = keep ? f1 : b1;
  }
  if (l == 0) out[OFF_CODES + R] = (float)fi;
  if (f2 - f1 > EPS) return;                     // unambiguous (wave-uniform)

  const int b = R >> 12, t = R & 4095;
  const float* drow = out + OFF_DIST + (size_t)R * 1024;
  float v[16];
#pragma unroll
  for (int k = 0; k < 16; ++k) v[k] = drow[k * 64 + l];
  float mn = 3.4e38f;
#pragma unroll
  for (int k = 0; k < 16; ++k) mn = fminf(mn, v[k]);
#pragma unroll
  for (int msk = 1; msk <= 32; msk <<= 1) mn = fminf(mn, __shfl_xor(mn, msk));
  const float thresh = mn + EPS;

  const double zd0 = (double)z[(size_t)b * 524288 + (size_t)l * 4096 + t];
  const double zd1 = (double)z[(size_t)b * 524288 + (size_t)(l + 64) * 4096 + t];
  const float szv = szf[R];

  float bestv = 3.4e38f; int bestj = 1 << 30;
#pragma unroll
  for (int k = 0; k < 16; ++k) {
    unsigned long long msk = __ballot(v[k] <= thresh);
    while (msk) {
      int s = __ffsll((unsigned long long)msk) - 1;
      msk &= msk - 1;
      int jc = k * 64 + s;
      float c0 = cb[(size_t)jc * 128 + l];
      float c1 = cb[(size_t)jc * 128 + 64 + l];
      double m = zd0 * (double)c0 + zd1 * (double)c1;
#pragma unroll
      for (int mm = 1; mm <= 32; mm <<= 1) m += __shfl_xor(m, mm);
      float m32 = (float)m;
      float dvex = (szv - 2.0f * m32) + scf[jc];
      if (dvex < bestv || (dvex == bestv && jc < bestj)) { bestv = dvex; bestj = jc; }
    }
  }
  if (l == 0) out[OFF_CODES + R] = (float)bestj;
}

// ---- z_q + loss ----
__global__ __launch_bounds__(256) void vq_out_kernel(
    const float* __restrict__ z, const float* __restrict__ cb,
    float* __restrict__ out, double* __restrict__ lacc)
{
  __shared__ int ci[128];
  __shared__ float cq[128][129];
  __shared__ double lw[4];
  const int tid = threadIdx.x;
  const int b  = blockIdx.x >> 5;
  const int t0 = (blockIdx.x & 31) * 128;
  const int R0 = b * 4096 + t0;
  if (tid < 128) ci[tid] = (int)out[OFF_CODES + R0 + tid];
  __syncthreads();
  for (int r = 0; r < 128; r += 2) {
    int row = r + (tid >> 7);
    int d = tid & 127;
    cq[row][d] = cb[(size_t)ci[row] * 128 + d];
  }
  __syncthreads();
  double ls = 0.0;
  for (int dp = 0; dp < 128; dp += 2) {
    int d = dp + (tid >> 7);
    int t = tid & 127;
    size_t o = (size_t)b * 524288 + (size_t)d * 4096 + t0 + t;
    float zv = z[o];
    float q = cq[t][d];
    __builtin_nontemporal_store(zv + (q - zv), out + o);  // straight-through f32
    double dd = (double)q - (double)zv;
    ls += dd * dd;
  }
#pragma unroll
  for (int msk = 1; msk <= 32; msk <<= 1) ls += __shfl_xor(ls, msk);
  if ((tid & 63) == 0) lw[tid >> 6] = ls;
  __syncthreads();
  if (tid == 0) atomicAdd(lacc, lw[0] + lw[1] + lw[2] + lw[3]);
}

__global__ void vq_fin(const double* lacc, float* out) {
  if (threadIdx.x == 0 && blockIdx.x == 0)
    out[OFF_LOSS] = (float)(*lacc * (1.25 / 4194304.0));
}

extern "C" void kernel_launch(void* const* d_in, const int* in_sizes, int n_in,
                              void* d_out, int out_size, void* d_ws, size_t ws_size,
                              hipStream_t stream) {
  const float* z  = (const float*)d_in[0];
  const float* cb = (const float*)d_in[1];
  float* out = (float*)d_out;
  char* ws = (char*)d_ws;
  double* lacc = (double*)(ws + WS_LACC);
  float* scf = (float*)(ws + WS_SCF);
  float* szf = (float*)(ws + WS_SZF);
  unsigned short* cbh = (unsigned short*)(ws + WS_CBH);
  float* pm1 = (float*)(ws + WS_PM1);
  float* pm2 = (float*)(ws + WS_PM2);
  int*   pi1 = (int*)(ws + WS_PI1);

  vq_prep<<<256, 256, 0, stream>>>(cb, cbh, scf, lacc);
  vq_main<<<4096, 256, 0, stream>>>(z, cbh, scf, szf, pm1, pm2, pi1, out);
  vq_refine<<<8192, 256, 0, stream>>>(z, cb, scf, szf, pm1, pm2, pi1, out);
  vq_out_kernel<<<256, 256, 0, stream>>>(z, cb, out, lacc);
  vq_fin<<<1, 64, 0, stream>>>(lacc, out);
}

// Round 7
// 78.956 us; speedup vs baseline: 1.7137x; 1.7137x over previous
//
#include <hip/hip_runtime.h>

typedef __attribute__((ext_vector_type(8))) short short8;
typedef __attribute__((ext_vector_type(4))) float f32x4;

namespace {
constexpr long long OFF_CODES = 4194304;        // 8*128*4096
constexpr long long OFF_LOSS  = 4227072;        // + 8*4096
constexpr long long OFF_DIST  = 4227073;
constexpr float EPS = 5e-4f;                    // > 2*max bf16-product dist err
// ws byte offsets (max end 532480 — well under proven ~2MB)
constexpr size_t WS_LACC = 0;
constexpr size_t WS_SCF  = 1024;                // 1024 f32
constexpr size_t WS_SZF  = 8192;                // 32768 f32 (ends 139264)
constexpr size_t WS_FLAG = 139264;              // 32768 u32 (ends 270336)
constexpr size_t WS_CBF  = 270336;              // 1024*128 u16 frag-ordered (ends 532480)
}

__device__ __forceinline__ unsigned short bf_rne(float v) {
  unsigned int u = __float_as_uint(v);
  unsigned int r = u + 0x7FFFu + ((u >> 16) & 1u);
  return (unsigned short)(r >> 16);
}

// ---- prep: codebook -> fragment-ordered bf16 + f32 norms; zero lacc ----
// cbf layout: ((g*4 + ks)*64 + lane)*8, g = j-group of 16, lane = (lg,lj),
// element e maps to cb[(g*16+lj)*128 + ks*32 + lg*8 + e].
__global__ __launch_bounds__(256) void vq_cbfrag(
    const float* __restrict__ cb, unsigned short* __restrict__ cbf,
    float* __restrict__ scf, double* lacc)
{
  __shared__ double pn[4][16];
  const int g = blockIdx.x;
  const int tid = threadIdx.x;
  const int ks = tid >> 6, l = tid & 63, lg = l >> 4, lj = l & 15;
  const float* src = cb + (size_t)(g * 16 + lj) * 128 + ks * 32 + lg * 8;
  double s = 0.0;
  short8 h;
#pragma unroll
  for (int e = 0; e < 8; ++e) {
    float v = src[e];
    float q = v * v;                             // f32 square (numpy chain)
    s += (double)q;
    h[e] = (short)bf_rne(v);
  }
  *reinterpret_cast<short8*>(cbf + (size_t)g * 2048 + (size_t)tid * 8) = h;
  s += __shfl_xor(s, 16);                        // reduce over lg (same lj)
  s += __shfl_xor(s, 32);
  if (lg == 0) pn[ks][lj] = s;
  __syncthreads();
  if (tid < 16)
    scf[g * 16 + tid] = (float)(pn[0][tid] + pn[1][tid] + pn[2][tid] + pn[3][tid]);
  if (blockIdx.x == 0 && tid == 0) *lacc = 0.0;
}

// ---- z row norms (f64 of f32 squares), coalesced [d][t] tile walk ----
__global__ __launch_bounds__(256) void vq_szf(
    const float* __restrict__ z, float* __restrict__ szf)
{
  __shared__ double pn[64][4];
  const int tid = threadIdx.x;
  const int R0 = blockIdx.x * 64;
  const int b = R0 >> 12, t0 = R0 & 4095;
  const int t = tid & 63, dg = tid >> 6;
  const float* zp = z + (size_t)b * 524288 + (size_t)dg * 32 * 4096 + t0 + t;
  double s = 0.0;
#pragma unroll
  for (int d = 0; d < 32; ++d) {
    float v = zp[(size_t)d * 4096];
    float q = v * v;
    s += (double)q;
  }
  pn[t][dg] = s;
  __syncthreads();
  if (tid < 64)
    szf[R0 + tid] = (float)(pn[tid][0] + pn[tid][1] + pn[tid][2] + pn[tid][3]);
}

// ---- main: 32 rows x 1024 j per block; coalesced frag B; quartered acc ----
__global__ __launch_bounds__(256, 4) void vq_main(
    const float* __restrict__ z, const unsigned short* __restrict__ cbf,
    const float* __restrict__ scf, const float* __restrict__ szf,
    unsigned int* __restrict__ flags, float* __restrict__ out)
{
  __shared__ __align__(16) unsigned short zh[32 * 136];
  __shared__ float scfl[1024];
  __shared__ float szl[32];
  __shared__ float rm1[4][32], rm2[4][32];
  __shared__ int   ri1[4][32];

  const int tid = threadIdx.x;
  const int R0 = blockIdx.x * 32;
  const int b = R0 >> 12, t0 = R0 & 4095;
  const float* zb = z + (size_t)b * 524288;

#pragma unroll
  for (int k = 0; k < 4; ++k) scfl[k * 256 + tid] = scf[k * 256 + tid];
  if (tid < 32) szl[tid] = szf[R0 + tid];

  {                                              // z -> bf16 LDS (no norms here)
    int t = tid & 31;
#pragma unroll
    for (int k = 0; k < 16; ++k) {
      int d = k * 8 + (tid >> 5);
      zh[t * 136 + d] = bf_rne(zb[(size_t)d * 4096 + t0 + t]);
    }
  }
  __syncthreads();

  const int w = tid >> 6, l = tid & 63, lj = l & 15, lg = l >> 4;

  short8 Ah[2][4];
#pragma unroll
  for (int tt = 0; tt < 2; ++tt)
#pragma unroll
    for (int ks = 0; ks < 4; ++ks)
      Ah[tt][ks] = *reinterpret_cast<const short8*>(
          &zh[(tt * 16 + lj) * 136 + ks * 32 + lg * 8]);
  float szr[2][4];
#pragma unroll
  for (int tt = 0; tt < 2; ++tt)
#pragma unroll
    for (int r = 0; r < 4; ++r) szr[tt][r] = szl[tt * 16 + lg * 4 + r];

  float m1[8], m2[8]; int i1[8];
#pragma unroll
  for (int s = 0; s < 8; ++s) { m1[s] = 3.4e38f; m2[s] = 3.4e38f; i1[s] = 0; }

  const unsigned short* pwave = cbf + (size_t)w * 16 * 2048 + (size_t)l * 8;

#pragma unroll 1
  for (int q = 0; q < 4; ++q) {
    f32x4 acc[2][4];
#pragma unroll
    for (int u = 0; u < 4; ++u) {
      acc[0][u] = (f32x4){0.f, 0.f, 0.f, 0.f};
      acc[1][u] = (f32x4){0.f, 0.f, 0.f, 0.f};
      const unsigned short* pg = pwave + (size_t)(q * 4 + u) * 2048;
#pragma unroll
      for (int ks = 0; ks < 4; ++ks) {
        short8 bh = *reinterpret_cast<const short8*>(pg + ks * 512); // (ks*64)*8
        acc[0][u] = __builtin_amdgcn_mfma_f32_16x16x32_bf16(Ah[0][ks], bh, acc[0][u], 0, 0, 0);
        acc[1][u] = __builtin_amdgcn_mfma_f32_16x16x32_bf16(Ah[1][ks], bh, acc[1][u], 0, 0, 0);
      }
    }
    // epilogue: numpy chain fl(fl(sz-2m)+sc), min1/min2, dist store
#pragma unroll
    for (int u = 0; u < 4; ++u) {
      const int jj = w * 256 + (q * 4 + u) * 16 + lj;
      const float sc = scfl[jj];
#pragma unroll
      for (int tt = 0; tt < 2; ++tt)
#pragma unroll
        for (int r = 0; r < 4; ++r) {
          float dv = (szr[tt][r] - 2.0f * acc[tt][u][r]) + sc;
          const int s = tt * 4 + r;
          bool lt1 = dv < m1[s];
          float o1 = m1[s];
          m2[s] = lt1 ? o1 : fminf(m2[s], dv);
          m1[s] = lt1 ? dv : o1;
          i1[s] = lt1 ? jj : i1[s];
          out[OFF_DIST + (size_t)(R0 + tt * 16 + lg * 4 + r) * 1024 + jj] = dv;
        }
    }
  }

  // in-wave 16-lane lexicographic (val,idx) reduce, tracking min2
#pragma unroll
  for (int s = 0; s < 8; ++s) {
    float a1 = m1[s]; int ai = i1[s]; float a2 = m2[s];
#pragma unroll
    for (int msk = 1; msk <= 8; msk <<= 1) {
      float b1 = __shfl_xor(a1, msk);
      int   bi = __shfl_xor(ai, msk);
      float b2 = __shfl_xor(a2, msk);
      bool keep = (a1 < b1) || (a1 == b1 && ai < bi);
      float lose = keep ? b1 : a1;
      a2 = fminf(fminf(a2, b2), lose);
      ai = keep ? ai : bi;
      a1 = keep ? a1 : b1;
    }
    if (lj == 0) {
      int t = (s >> 2) * 16 + lg * 4 + (s & 3);
      rm1[w][t] = a1; ri1[w][t] = ai; rm2[w][t] = a2;
    }
  }
  __syncthreads();
  if (tid < 32) {                                // merge 4 waves (j ascending)
    float f1 = rm1[0][tid]; int fi = ri1[0][tid]; float f2 = rm2[0][tid];
#pragma unroll
    for (int ww = 1; ww < 4; ++ww) {
      float b1 = rm1[ww][tid]; int bi = ri1[ww][tid]; float b2 = rm2[ww][tid];
      bool keep = (f1 < b1) || (f1 == b1 && fi < bi);
      float lose = keep ? b1 : f1;
      f2 = fminf(fminf(f2, b2), lose);
      fi = keep ? fi : bi;
      f1 = keep ? f1 : b1;
    }
    int R = R0 + tid;
    out[OFF_CODES + R] = (float)fi;
    flags[R] = (f2 - f1 <= EPS) ? 1u : 0u;
  }
}

// ---- refine: flagged rows -> exact f64 dot + exact f32 chain, lex argmin ----
__global__ __launch_bounds__(256) void vq_refine(
    const float* __restrict__ z, const float* __restrict__ cb,
    const float* __restrict__ scf, const float* __restrict__ szf,
    const unsigned int* __restrict__ flags, float* __restrict__ out)
{
  const int w = threadIdx.x >> 6, l = threadIdx.x & 63;
  const int R = blockIdx.x * 4 + w;
  if (!flags[R]) return;
  const int b = R >> 12, t = R & 4095;

  const float* drow = out + OFF_DIST + (size_t)R * 1024;
  float v[16];
#pragma unroll
  for (int k = 0; k < 16; ++k) v[k] = drow[k * 64 + l];
  float mn = 3.4e38f;
#pragma unroll
  for (int k = 0; k < 16; ++k) mn = fminf(mn, v[k]);
#pragma unroll
  for (int msk = 1; msk <= 32; msk <<= 1) mn = fminf(mn, __shfl_xor(mn, msk));
  const float thresh = mn + EPS;

  const double zd0 = (double)z[(size_t)b * 524288 + (size_t)l * 4096 + t];
  const double zd1 = (double)z[(size_t)b * 524288 + (size_t)(l + 64) * 4096 + t];
  const float szv = szf[R];

  float bestv = 3.4e38f; int bestj = 1 << 30;
#pragma unroll
  for (int k = 0; k < 16; ++k) {
    unsigned long long msk = __ballot(v[k] <= thresh);
    while (msk) {
      int s = __ffsll((unsigned long long)msk) - 1;
      msk &= msk - 1;
      int jc = k * 64 + s;
      float c0 = cb[(size_t)jc * 128 + l];
      float c1 = cb[(size_t)jc * 128 + 64 + l];
      double m = zd0 * (double)c0 + zd1 * (double)c1;
#pragma unroll
      for (int mm = 1; mm <= 32; mm <<= 1) m += __shfl_xor(m, mm);
      float m32 = (float)m;
      float dvex = (szv - 2.0f * m32) + scf[jc];
      if (dvex < bestv || (dvex == bestv && jc < bestj)) { bestv = dvex; bestj = jc; }
    }
  }
  if (l == 0) out[OFF_CODES + R] = (float)bestj;
}

// ---- z_q + loss ----
__global__ __launch_bounds__(256) void vq_out_kernel(
    const float* __restrict__ z, const float* __restrict__ cb,
    float* __restrict__ out, double* __restrict__ lacc)
{
  __shared__ int ci[128];
  __shared__ float cq[128][129];
  __shared__ double lw[4];
  const int tid = threadIdx.x;
  const int b  = blockIdx.x >> 5;
  const int t0 = (blockIdx.x & 31) * 128;
  const int R0 = b * 4096 + t0;
  if (tid < 128) ci[tid] = (int)out[OFF_CODES + R0 + tid];
  __syncthreads();
  for (int r = 0; r < 128; r += 2) {
    int row = r + (tid >> 7);
    int d = tid & 127;
    cq[row][d] = cb[(size_t)ci[row] * 128 + d];
  }
  __syncthreads();
  double ls = 0.0;
  for (int dp = 0; dp < 128; dp += 2) {
    int d = dp + (tid >> 7);
    int t = tid & 127;
    size_t o = (size_t)b * 524288 + (size_t)d * 4096 + t0 + t;
    float zv = z[o];
    float q = cq[t][d];
    out[o] = zv + (q - zv);                      // straight-through f32 chain
    double dd = (double)q - (double)zv;
    ls += dd * dd;
  }
#pragma unroll
  for (int msk = 1; msk <= 32; msk <<= 1) ls += __shfl_xor(ls, msk);
  if ((tid & 63) == 0) lw[tid >> 6] = ls;
  __syncthreads();
  if (tid == 0) atomicAdd(lacc, lw[0] + lw[1] + lw[2] + lw[3]);
}

__global__ void vq_fin(const double* lacc, float* out) {
  if (threadIdx.x == 0 && blockIdx.x == 0)
    out[OFF_LOSS] = (float)(*lacc * (1.25 / 4194304.0));
}

extern "C" void kernel_launch(void* const* d_in, const int* in_sizes, int n_in,
                              void* d_out, int out_size, void* d_ws, size_t ws_size,
                              hipStream_t stream) {
  const float* z  = (const float*)d_in[0];
  const float* cb = (const float*)d_in[1];
  float* out = (float*)d_out;
  char* ws = (char*)d_ws;
  double* lacc = (double*)(ws + WS_LACC);
  float* scf = (float*)(ws + WS_SCF);
  float* szf = (float*)(ws + WS_SZF);
  unsigned int* flags = (unsigned int*)(ws + WS_FLAG);
  unsigned short* cbf = (unsigned short*)(ws + WS_CBF);

  vq_cbfrag<<<64, 256, 0, stream>>>(cb, cbf, scf, lacc);
  vq_szf<<<512, 256, 0, stream>>>(z, szf);
  vq_main<<<1024, 256, 0, stream>>>(z, cbf, scf, szf, flags, out);
  vq_refine<<<8192, 256, 0, stream>>>(z, cb, scf, szf, flags, out);
  vq_out_kernel<<<256, 256, 0, stream>>>(z, cb, out, lacc);
  vq_fin<<<1, 64, 0, stream>>>(lacc, out);
}